// Round 1
// baseline (235.553 us; speedup 1.0000x reference)
//
#include <hip/hip_runtime.h>

#define DEPTH 6
#define NQ 18
// wire w <-> global bit (17 - w); bit 17 = MSB = wire 0 (PennyLane order)

__device__ __forceinline__ float2 cmul(float2 a, float2 b){
  return make_float2(a.x*b.x - a.y*b.y, a.x*b.y + a.y*b.x);
}
__device__ __forceinline__ float2 cadd(float2 a, float2 b){
  return make_float2(a.x + b.x, a.y + b.y);
}

struct M2 { float2 m00, m01, m10, m11; };

__device__ __forceinline__ M2 mmul(const M2& A, const M2& B){
  M2 C;
  C.m00 = cadd(cmul(A.m00,B.m00), cmul(A.m01,B.m10));
  C.m01 = cadd(cmul(A.m00,B.m01), cmul(A.m01,B.m11));
  C.m10 = cadd(cmul(A.m10,B.m00), cmul(A.m11,B.m10));
  C.m11 = cadd(cmul(A.m10,B.m01), cmul(A.m11,B.m11));
  return C;
}
__device__ __forceinline__ M2 mrx(float t){
  float c = cosf(0.5f*t), s = sinf(0.5f*t);
  M2 R; R.m00 = make_float2(c,0.f); R.m01 = make_float2(0.f,-s);
        R.m10 = make_float2(0.f,-s); R.m11 = make_float2(c,0.f);
  return R;
}
__device__ __forceinline__ M2 mry(float t){
  float c = cosf(0.5f*t), s = sinf(0.5f*t);
  M2 R; R.m00 = make_float2(c,0.f); R.m01 = make_float2(-s,0.f);
        R.m10 = make_float2(s,0.f); R.m11 = make_float2(c,0.f);
  return R;
}
__device__ __forceinline__ M2 mrz(float t){
  float c = cosf(0.5f*t), s = sinf(0.5f*t);
  M2 R; R.m00 = make_float2(c,-s); R.m01 = make_float2(0.f,0.f);
        R.m10 = make_float2(0.f,0.f); R.m11 = make_float2(c,s);
  return R;
}

// One thread per (layer, wire): fused U = Rz*Ry*Rx (layer 0 also absorbs basis).
__global__ void prep_k(const float* __restrict__ params, const float* __restrict__ basis,
                       float2* __restrict__ mats, float* __restrict__ acc){
  int id = threadIdx.x;
  if (id == 0) *acc = 0.0f;          // ws is re-poisoned 0xAA before every launch
  if (id >= DEPTH*NQ) return;
  int l = id / NQ, w = id % NQ;
  const float* p = params + id*3;
  M2 U = mmul(mrz(p[2]), mmul(mry(p[1]), mrx(p[0])));
  if (l == 0){
    const float* b = basis + w*3;
    M2 B = mmul(mrz(b[2]), mmul(mry(b[1]), mrx(b[0])));
    U = mmul(U, B);                  // basis applied first -> right-multiply
  }
  float2* o = mats + id*4;
  o[0]=U.m00; o[1]=U.m01; o[2]=U.m10; o[3]=U.m11;
}

// Apply a 2x2 gate on local bit b of a 4096-amp LDS tile. 2048 pairs, 256 thr.
__device__ __forceinline__ void apply_gate(float2* s, int t, int b,
                                           float2 u00, float2 u01, float2 u10, float2 u11){
  #pragma unroll
  for (int k = 0; k < 8; ++k){
    int p  = t + k*256;
    int i0 = ((p >> b) << (b+1)) | (p & ((1 << b) - 1));
    int i1 = i0 | (1 << b);
    float2 a0 = s[i0], a1 = s[i1];
    s[i0] = cadd(cmul(u00,a0), cmul(u01,a1));
    s[i1] = cadd(cmul(u10,a0), cmul(u11,a1));
  }
}

// LOW pass: contiguous tile, global bits 11..0 local. Optionally applies the
// previous layer's CNOT chain w=6..16 as a prefix-XOR index permutation at
// load time, then gates on wires 6..17 of `layer`.
// flags: bit0 = init |0..0>, bit1 = apply CNOT permutation on load.
__global__ __launch_bounds__(256) void pass_low(float2* __restrict__ st,
                                                const float2* __restrict__ mats,
                                                int layer, int flags){
  __shared__ float2 s[4096];
  const int t = threadIdx.x;
  const unsigned base = (unsigned)blockIdx.x << 12;
  if (flags & 1){
    #pragma unroll
    for (int k=0;k<16;k++) s[t + k*256] = make_float2(0.f,0.f);
    if (blockIdx.x == 0 && t == 0) s[0] = make_float2(1.f,0.f);
  } else {
    #pragma unroll
    for (int k=0;k<16;k++){
      unsigned a = t + k*256;
      unsigned d = a;
      if (flags & 2){ d ^= d>>1; d ^= d>>2; d ^= d>>4; d ^= d>>8; } // chain perm
      s[d] = st[base + a];
    }
  }
  __syncthreads();
  const float2* M = mats + (layer*NQ + 6)*4;
  for (int w = 6; w < 18; ++w){
    const int b = 17 - w;                 // local bit
    float2 u00 = M[0], u01 = M[1], u10 = M[2], u11 = M[3]; M += 4;
    apply_gate(s, t, b, u00, u01, u10, u11);
    __syncthreads();
  }
  #pragma unroll
  for (int k=0;k<16;k++){ unsigned a = t + k*256; st[base + a] = s[a]; }
}

// HIGH pass: tile covers global bits 17..11 (7) + 4..0 (5). Gates on wires
// 0..5 (local bits 11..6). Then either: store with CNOT chain w=0..5 folded
// into a prefix-XOR permutation of the high 7 bits, OR (finalpass) reduce
// <Z0> = sum of +/-|amp|^2 by local bit 11 (= global bit 17 = wire 0); the
// remaining layer-5 CNOTs preserve each bit-17 half's norm, so they're skipped.
__global__ __launch_bounds__(256) void pass_high(float2* __restrict__ st,
                                                 const float2* __restrict__ mats,
                                                 int layer, int finalpass,
                                                 float* __restrict__ acc){
  __shared__ float2 s[4096];
  const int t = threadIdx.x;
  const unsigned blk = blockIdx.x;            // global bits 10..5
  #pragma unroll
  for (int k=0;k<16;k++){
    unsigned a = t + k*256;
    unsigned lo = a & 31u, h = a >> 5;        // h = global bits 17..11
    s[a] = st[(h << 11) | (blk << 5) | lo];
  }
  __syncthreads();
  const float2* M = mats + (layer*NQ)*4;
  for (int w = 0; w < 6; ++w){
    const int b = 11 - w;                     // local bit for wire w
    float2 u00 = M[0], u01 = M[1], u10 = M[2], u11 = M[3]; M += 4;
    apply_gate(s, t, b, u00, u01, u10, u11);
    __syncthreads();
  }
  if (finalpass){
    float part = 0.f;
    #pragma unroll
    for (int k=0;k<16;k++){
      unsigned a = t + k*256;
      float2 v = s[a];
      float pr = v.x*v.x + v.y*v.y;
      part += (a & 2048u) ? -pr : pr;         // local bit 11 == wire 0
    }
    #pragma unroll
    for (int off = 32; off > 0; off >>= 1) part += __shfl_down(part, off, 64);
    __shared__ float wsum[4];
    if ((t & 63) == 0) wsum[t >> 6] = part;
    __syncthreads();
    if (t == 0) atomicAdd(acc, wsum[0]+wsum[1]+wsum[2]+wsum[3]);
  } else {
    #pragma unroll
    for (int k=0;k<16;k++){
      unsigned a = t + k*256;
      unsigned lo = a & 31u, h = a >> 5;
      unsigned z = h; z ^= z>>1; z ^= z>>2; z ^= z>>4;   // CNOT chain w=0..5
      st[(z << 11) | (blk << 5) | lo] = s[a];
    }
  }
}

__global__ void bcast_k(const float* __restrict__ acc, float* __restrict__ out, int n){
  int i = blockIdx.x*blockDim.x + threadIdx.x;
  if (i < n) out[i] = *acc;
}

extern "C" void kernel_launch(void* const* d_in, const int* in_sizes, int n_in,
                              void* d_out, int out_size, void* d_ws, size_t ws_size,
                              hipStream_t stream){
  (void)in_sizes; (void)n_in; (void)ws_size;
  const float* params = (const float*)d_in[1];   // (6,18,3)
  const float* basis  = (const float*)d_in[2];   // (18,3)
  float* out = (float*)d_out;                    // 32 floats
  char* ws = (char*)d_ws;
  float*  acc  = (float*)ws;                     // 1 float accumulator
  float2* mats = (float2*)(ws + 256);            // 108 * 4 complex
  float2* st   = (float2*)(ws + 4096);           // 2^18 complex = 2 MB

  prep_k<<<1, 128, 0, stream>>>(params, basis, mats, acc);
  // init |0>, gates layer 0 (basis-fused) on wires 6..17
  pass_low<<<64, 256, 0, stream>>>(st, mats, 0, 1);
  for (int l = 0; l < 5; ++l){
    // gates layer l wires 0..5, then CNOTs w=0..5 (store perm)
    pass_high<<<64, 256, 0, stream>>>(st, mats, l, 0, acc);
    // CNOTs w=6..16 of layer l (load perm), then gates layer l+1 wires 6..17
    pass_low<<<64, 256, 0, stream>>>(st, mats, l + 1, 2);
  }
  // gates layer 5 wires 0..5, then reduce <Z0> (remaining CNOTs norm-preserving)
  pass_high<<<64, 256, 0, stream>>>(st, mats, 5, 1, acc);
  bcast_k<<<1, 64, 0, stream>>>(acc, out, out_size);
}

// Round 2
// 61.669 us; speedup vs baseline: 3.8196x; 3.8196x over previous
//
#include <hip/hip_runtime.h>

// <Z0> of the 18-qubit circuit == <Z0> of its 6-qubit backward light cone:
//   Z0 commutes with Z-control CNOTs, so the last chain cancels; each earlier
//   chain grows Pauli support by exactly 1 wire (backward order hits CN(w,w+1)
//   before CN(w-1,w)). After 6 layers + basis: support = wires 0..5.
// Simulate 64 amplitudes, one per lane of a single wave.
// wire w <-> bit (5-w); bit 5 = MSB = wire 0 (PennyLane reshape order).

__device__ __forceinline__ float2 cmul(float2 a, float2 b){
  return make_float2(a.x*b.x - a.y*b.y, a.x*b.y + a.y*b.x);
}
__device__ __forceinline__ float2 cadd(float2 a, float2 b){
  return make_float2(a.x + b.x, a.y + b.y);
}
struct M2 { float2 m00, m01, m10, m11; };
__device__ __forceinline__ M2 mmul(const M2& A, const M2& B){
  M2 C;
  C.m00 = cadd(cmul(A.m00,B.m00), cmul(A.m01,B.m10));
  C.m01 = cadd(cmul(A.m00,B.m01), cmul(A.m01,B.m11));
  C.m10 = cadd(cmul(A.m10,B.m00), cmul(A.m11,B.m10));
  C.m11 = cadd(cmul(A.m10,B.m01), cmul(A.m11,B.m11));
  return C;
}
__device__ __forceinline__ M2 mrx(float t){
  float c = cosf(0.5f*t), s = sinf(0.5f*t);
  M2 R; R.m00 = make_float2(c,0.f);  R.m01 = make_float2(0.f,-s);
        R.m10 = make_float2(0.f,-s); R.m11 = make_float2(c,0.f);
  return R;
}
__device__ __forceinline__ M2 mry(float t){
  float c = cosf(0.5f*t), s = sinf(0.5f*t);
  M2 R; R.m00 = make_float2(c,0.f); R.m01 = make_float2(-s,0.f);
        R.m10 = make_float2(s,0.f); R.m11 = make_float2(c,0.f);
  return R;
}
__device__ __forceinline__ M2 mrz(float t){
  float c = cosf(0.5f*t), s = sinf(0.5f*t);
  M2 R; R.m00 = make_float2(c,-s);    R.m01 = make_float2(0.f,0.f);
        R.m10 = make_float2(0.f,0.f); R.m11 = make_float2(c,s);
  return R;
}

__global__ __launch_bounds__(64) void sim_lc(const float* __restrict__ params,
                                             const float* __restrict__ basis,
                                             float* __restrict__ out, int n){
  __shared__ float2 mats[42][4];   // 6 basis + 6 layers x 6 wires, fused Rz*Ry*Rx
  const int lane = threadIdx.x;

  // phase 1: build the 42 fused matrices in parallel (one per lane)
  if (lane < 42){
    const float* p;
    if (lane < 6) p = basis + lane*3;
    else { int g = lane - 6; int l = g/6, w = g%6; p = params + (l*18 + w)*3; }
    M2 U = mmul(mrz(p[2]), mmul(mry(p[1]), mrx(p[0])));
    mats[lane][0]=U.m00; mats[lane][1]=U.m01; mats[lane][2]=U.m10; mats[lane][3]=U.m11;
  }
  __syncthreads();

  // phase 2: 64-amplitude simulation, amp (ax,ay) lives in this lane
  float ax = (lane == 0) ? 1.f : 0.f, ay = 0.f;

  auto gate = [&](int gi, int w){
    float2 u00 = mats[gi][0], u01 = mats[gi][1], u10 = mats[gi][2], u11 = mats[gi][3];
    const int bm = 1 << (5 - w);
    float px = __shfl_xor(ax, bm, 64);
    float py = __shfl_xor(ay, bm, 64);
    const bool hi = (lane & bm) != 0;
    // new[a] = U[a][0]*amp(bit=0) + U[a][1]*amp(bit=1)
    float lx = hi ? px : ax, ly = hi ? py : ay;   // amp with wire bit = 0
    float hx = hi ? ax : px, hy = hi ? ay : py;   // amp with wire bit = 1
    float2 c0 = hi ? u10 : u00, c1 = hi ? u11 : u01;
    ax = c0.x*lx - c0.y*ly + c1.x*hx - c1.y*hy;
    ay = c0.x*ly + c0.y*lx + c1.x*hy + c1.y*hx;
  };

  #pragma unroll
  for (int w = 0; w < 6; ++w) gate(w, w);                     // basis rotation
  #pragma unroll
  for (int l = 0; l < 6; ++l){
    #pragma unroll
    for (int w = 0; w < 6; ++w) gate(6 + l*6 + w, w);         // layer 1q gates
    #pragma unroll
    for (int w = 0; w < 5; ++w){                              // CNOT chain w=0..4
      // control bit 5-w, target bit 4-w: pull from index with target flipped
      int src = lane ^ (((lane >> (5 - w)) & 1) << (4 - w));
      ax = __shfl(ax, src, 64);
      ay = __shfl(ay, src, 64);
    }
  }

  // <Z0> = sum (+/-)|amp|^2, sign by bit 5 (wire 0)
  float pr = ax*ax + ay*ay;
  float part = (lane & 32) ? -pr : pr;
  #pragma unroll
  for (int off = 32; off; off >>= 1) part += __shfl_xor(part, off, 64);
  if (lane < n) out[lane] = part;
}

extern "C" void kernel_launch(void* const* d_in, const int* in_sizes, int n_in,
                              void* d_out, int out_size, void* d_ws, size_t ws_size,
                              hipStream_t stream){
  (void)in_sizes; (void)n_in; (void)d_ws; (void)ws_size;
  const float* params = (const float*)d_in[1];   // (6,18,3) — only wires 0..5 read
  const float* basis  = (const float*)d_in[2];   // (18,3)   — only wires 0..5 read
  float* out = (float*)d_out;                    // 32 floats, all identical
  sim_lc<<<1, 64, 0, stream>>>(params, basis, out, out_size);
}

// Round 3
// 58.867 us; speedup vs baseline: 4.0015x; 1.0476x over previous
//
#include <hip/hip_runtime.h>

// <Z0> of the 18-qubit circuit == <Z0> of its 6-qubit backward light cone
// (validated round 2, absmax 0.0). This version additionally virtualizes the
// CNOT chains: they are linear maps over GF(2)^6 of the index bits, so instead
// of shuffling amplitudes we track phi (storage lane = phi(true index)) and
// rewrite each 1q gate as shfl_xor with mask V[b]=phi(e_b) and a hi-flag
// parity(lane & R[b]) with R[b] = row b of phi^-1. All masks are constexpr.
// wire w <-> true bit (5-w); bit 5 = MSB = wire 0 (PennyLane order).

struct Masks { unsigned m[42]; unsigned r[42]; unsigned z; };

constexpr Masks make_masks(){
  Masks M{};
  unsigned V[6], R[6];
  for (int b = 0; b < 6; ++b){ V[b] = 1u << b; R[b] = 1u << b; }
  int g = 0;
  // basis rotations, wires 0..5 (phi = I here)
  for (int w = 0; w < 6; ++w){ int b = 5 - w; M.m[g] = V[b]; M.r[g] = R[b]; ++g; }
  for (int l = 0; l < 6; ++l){
    // layer 1q gates (before this layer's chain)
    for (int w = 0; w < 6; ++w){ int b = 5 - w; M.m[g] = V[b]; M.r[g] = R[b]; ++g; }
    // chain c: y_b = XOR_{j>=b} x_j  =>  c^-1(e_b) = e_b ^ e_{b-1}
    // phi' = phi o c^-1  : V'[b] = V[b] ^ V[b-1]   (old V[b-1]; descend)
    for (int b = 5; b >= 1; --b) V[b] ^= V[b-1];
    // phi'^-1 = c o phi^-1 : R'[b] = R[b] ^ R'[b+1] (new R[b+1]; descend)
    for (int b = 4; b >= 0; --b) R[b] ^= R[b+1];
  }
  M.z = R[5];   // final sign mask for <Z0> (row 5 is chain-invariant)
  return M;
}
constexpr Masks MK = make_masks();

__device__ __forceinline__ float2 cmul(float2 a, float2 b){
  return make_float2(a.x*b.x - a.y*b.y, a.x*b.y + a.y*b.x);
}
__device__ __forceinline__ float2 cadd(float2 a, float2 b){
  return make_float2(a.x + b.x, a.y + b.y);
}
struct M2 { float2 m00, m01, m10, m11; };
__device__ __forceinline__ M2 mmul(const M2& A, const M2& B){
  M2 C;
  C.m00 = cadd(cmul(A.m00,B.m00), cmul(A.m01,B.m10));
  C.m01 = cadd(cmul(A.m00,B.m01), cmul(A.m01,B.m11));
  C.m10 = cadd(cmul(A.m10,B.m00), cmul(A.m11,B.m10));
  C.m11 = cadd(cmul(A.m10,B.m01), cmul(A.m11,B.m11));
  return C;
}
__device__ __forceinline__ M2 mrx(float t){
  float c = cosf(0.5f*t), s = sinf(0.5f*t);
  M2 R; R.m00 = make_float2(c,0.f);  R.m01 = make_float2(0.f,-s);
        R.m10 = make_float2(0.f,-s); R.m11 = make_float2(c,0.f);
  return R;
}
__device__ __forceinline__ M2 mry(float t){
  float c = cosf(0.5f*t), s = sinf(0.5f*t);
  M2 R; R.m00 = make_float2(c,0.f); R.m01 = make_float2(-s,0.f);
        R.m10 = make_float2(s,0.f); R.m11 = make_float2(c,0.f);
  return R;
}
__device__ __forceinline__ M2 mrz(float t){
  float c = cosf(0.5f*t), s = sinf(0.5f*t);
  M2 R; R.m00 = make_float2(c,-s);    R.m01 = make_float2(0.f,0.f);
        R.m10 = make_float2(0.f,0.f); R.m11 = make_float2(c,s);
  return R;
}

__global__ __launch_bounds__(64) void sim_lc(const float* __restrict__ params,
                                             const float* __restrict__ basis,
                                             float* __restrict__ out, int n){
  __shared__ float2 mats[42][4];   // 6 basis + 6 layers x 6 wires, fused Rz*Ry*Rx
  const int lane = threadIdx.x;

  // phase 1: build the 42 fused matrices in parallel (one per lane)
  if (lane < 42){
    const float* p;
    if (lane < 6) p = basis + lane*3;
    else { int g = lane - 6; int l = g/6, w = g%6; p = params + (l*18 + w)*3; }
    M2 U = mmul(mrz(p[2]), mmul(mry(p[1]), mrx(p[0])));
    mats[lane][0]=U.m00; mats[lane][1]=U.m01; mats[lane][2]=U.m10; mats[lane][3]=U.m11;
  }
  __syncthreads();

  // phase 2: 64 amplitudes, one per lane; CNOTs are free (index relabeling)
  float ax = (lane == 0) ? 1.f : 0.f, ay = 0.f;

  #pragma unroll
  for (int g = 0; g < 42; ++g){
    const int m = (int)MK.m[g];
    const int r = (int)MK.r[g];
    float2 u00 = mats[g][0], u01 = mats[g][1], u10 = mats[g][2], u11 = mats[g][3];
    float px = __shfl_xor(ax, m, 64);
    float py = __shfl_xor(ay, m, 64);
    const bool hi = (__popc(lane & r) & 1) != 0;
    // new = A*self + B*partner;  lo: u00*self + u01*partner, hi: u11*self + u10*partner
    float2 A = hi ? u11 : u00;
    float2 B = hi ? u10 : u01;
    float nx = A.x*ax - A.y*ay + B.x*px - B.y*py;
    float ny = A.x*ay + A.y*ax + B.x*py + B.y*px;
    ax = nx; ay = ny;
  }

  // <Z0> = sum (+/-)|amp|^2, sign = parity(lane & z) (bit 5 of true index)
  float pr = ax*ax + ay*ay;
  float part = (__popc(lane & (int)MK.z) & 1) ? -pr : pr;
  #pragma unroll
  for (int off = 32; off; off >>= 1) part += __shfl_xor(part, off, 64);
  if (lane < n) out[lane] = part;
}

extern "C" void kernel_launch(void* const* d_in, const int* in_sizes, int n_in,
                              void* d_out, int out_size, void* d_ws, size_t ws_size,
                              hipStream_t stream){
  (void)in_sizes; (void)n_in; (void)d_ws; (void)ws_size;
  const float* params = (const float*)d_in[1];   // (6,18,3) — only wires 0..5 read
  const float* basis  = (const float*)d_in[2];   // (18,3)   — only wires 0..5 read
  float* out = (float*)d_out;                    // 32 floats, all identical
  sim_lc<<<1, 64, 0, stream>>>(params, basis, out, out_size);
}